// Round 7
// baseline (91.875 us; speedup 1.0000x reference)
//
#include <hip/hip_runtime.h>

#define TPB   256
#define BINT  64     // bin kernel block size: 64-thr blocks spread over 256 CUs
#define MAXB  8
#define GD    20
#define NC    (GD * GD * GD)
#define CAP   16     // Poisson(2.05) max over 8000 cells ~13; P(>16) ~ 6e-7. 2MB bins.

static inline int cdiv(int a, int b) { return (a + b - 1) / b; }

// --- persistent (non-poisoned) state ----------------------------------------
// The harness poisons d_ws each iteration; static __device__ globals survive.
// g_counts[cell] = (gen<<8) | cnt : stale generations read as count 0, so the
// counts memset dispatch is eliminated entirely (3 dispatches -> 2).
// Generation hand-off (no intra-kernel ordering hazards):
//   prev query's last block bumps g_gen -> bin reads g_gen (stable: writer ran
//   in an earlier dispatch), publishes to g_gen_q -> query reads g_gen_q
//   (stable: only bin writes it). First iteration: g_gen=1, tags=0 (invalid).
__device__ unsigned g_counts[NC];     // zero-init at module load
__device__ unsigned g_gen   = 1u;     // generation for the next bin pass
__device__ unsigned g_gen_q = 0u;     // generation the current query validates
__device__ unsigned g_done  = 0u;     // query block-completion ticket

// --- DPP cross-lane helpers (rocPRIM wave64 pattern) ------------------------
// NB: __builtin_amdgcn_update_dpp requires LITERAL ctrl/rmask -> macros/templates.
#define DPP_ADD_I(x, ctrl, rmask)                                             \
    ((x) + __builtin_amdgcn_update_dpp(0, (x), (ctrl), (rmask), 0xf, true))
#define DPP_ADD_F(x, ctrl, rmask)                                             \
    ((x) + __int_as_float(__builtin_amdgcn_update_dpp(                        \
               0, __float_as_int(x), (ctrl), (rmask), 0xf, true)))

__device__ __forceinline__ int wave_incl_scan_i(int x) {
    x = DPP_ADD_I(x, 0x111, 0xf);   // row_shr:1
    x = DPP_ADD_I(x, 0x112, 0xf);   // row_shr:2
    x = DPP_ADD_I(x, 0x114, 0xf);   // row_shr:4
    x = DPP_ADD_I(x, 0x118, 0xf);   // row_shr:8
    x = DPP_ADD_I(x, 0x142, 0xa);   // row_bcast:15
    x = DPP_ADD_I(x, 0x143, 0xc);   // row_bcast:31
    return x;
}

template <int CTRL, int RMASK>
__device__ __forceinline__ int dpp_max_step(int x) {
    const int y = __builtin_amdgcn_update_dpp(0, x, CTRL, RMASK, 0xf, true);
    return ((unsigned)x > (unsigned)y) ? x : y;
}
__device__ __forceinline__ int wave_incl_maxscan_u(int x) {
    x = dpp_max_step<0x111, 0xf>(x);
    x = dpp_max_step<0x112, 0xf>(x);
    x = dpp_max_step<0x114, 0xf>(x);
    x = dpp_max_step<0x118, 0xf>(x);
    x = dpp_max_step<0x142, 0xa>(x);
    x = dpp_max_step<0x143, 0xc>(x);
    return x;
}

__device__ __forceinline__ float wave_sum_f(float x) {
    x = DPP_ADD_F(x, 0x111, 0xf);
    x = DPP_ADD_F(x, 0x112, 0xf);
    x = DPP_ADD_F(x, 0x114, 0xf);
    x = DPP_ADD_F(x, 0x118, 0xf);
    x = DPP_ADD_F(x, 0x142, 0xa);
    x = DPP_ADD_F(x, 0x143, 0xc);
    return __int_as_float(__builtin_amdgcn_readlane(__float_as_int(x), 63));
}

// --- bin + transpose kernel (round-4 hot loop + tagged-CAS slot alloc) ------
__global__ void __launch_bounds__(BINT) bin_kernel(
    const float* __restrict__ x, const float* __restrict__ ip,
    float4* __restrict__ bins, float* __restrict__ xT, int B, int n_in)
{
    const unsigned gen = g_gen & 0xFFFFFFu;
    if (blockIdx.x == 0 && threadIdx.x == 0) g_gen_q = gen;  // publish to query

    const int i = blockIdx.x * BINT + (int)threadIdx.x;
    if (i >= n_in) return;
    const float px = ip[3 * i], py = ip[3 * i + 1], pz = ip[3 * i + 2];
    const int cx = min(GD - 1, max(0, (int)(px * (float)GD)));
    const int cy = min(GD - 1, max(0, (int)(py * (float)GD)));
    const int cz = min(GD - 1, max(0, (int)(pz * (float)GD)));
    const int cell = (cx * GD + cy) * GD + cz;

    // Tagged slot allocation: stale tag -> restart count at this generation.
    int slot;
    unsigned expected = g_counts[cell];
    while (true) {
        unsigned newval;
        if ((expected >> 8) == gen) {
            slot = (int)(expected & 0xFFu);
            newval = (slot >= 0xFF) ? expected : expected + 1u;
        } else {
            slot = 0;
            newval = (gen << 8) | 1u;
        }
        const unsigned prev = atomicCAS(&g_counts[cell], expected, newval);
        if (prev == expected) break;
        expected = prev;
    }
    if (slot < CAP)   // query clamps count to CAP; overflow prob ~6e-7
        bins[(size_t)cell * CAP + slot] = make_float4(px, py, pz, __int_as_float(i));

    float v[MAXB];
#pragma unroll
    for (int b = 0; b < MAXB; ++b)
        v[b] = (b < B) ? x[(size_t)b * n_in + i] : 0.0f;
    float4* dst = (float4*)(xT + (size_t)i * MAXB);
    dst[0] = make_float4(v[0], v[1], v[2], v[3]);
    dst[1] = make_float4(v[4], v[5], v[6], v[7]);
}

// --- query kernel: one wave per output point (round-4 body + tag check) -----
__global__ void __launch_bounds__(TPB) query_kernel(
    const float4* __restrict__ bins, const float* __restrict__ xT,
    const float* __restrict__ out_pos, float* __restrict__ out,
    int B, int n_out, float r2)
{
    // Per-wave 64-slot scatter buffer for owner resolution (1 KB/block).
    __shared__ int Msh[TPB / 64][64];

    const unsigned gen = g_gen_q;                 // stable: only bin writes it
    const int lane = (int)threadIdx.x & 63;
    const int wid  = (int)threadIdx.x >> 6;
    const int o    = blockIdx.x * 4 + wid;

    if (o < n_out) {                              // no early return: ticket below
        volatile int* M = &Msh[wid][0];

        const float ox = out_pos[3 * o];
        const float oy = out_pos[3 * o + 1];
        const float oz = out_pos[3 * o + 2];

        // Cell ranges from [o-r-m, o+r+m]; margin m covers fp slop on the
        // d2<=r2 boundary. Worst span 4 cells/axis -> ncell<=64.
        const float m = 0.05f + 1e-4f;
        const int cxlo = max(0, (int)floorf((ox - m) * (float)GD));
        const int cxhi = min(GD - 1, (int)floorf((ox + m) * (float)GD));
        const int cylo = max(0, (int)floorf((oy - m) * (float)GD));
        const int cyhi = min(GD - 1, (int)floorf((oy + m) * (float)GD));
        const int czlo = max(0, (int)floorf((oz - m) * (float)GD));
        const int czhi = min(GD - 1, (int)floorf((oz + m) * (float)GD));
        const int nx = cxhi - cxlo + 1, ny = cyhi - cylo + 1, nz = czhi - czlo + 1;
        const int ncell = nx * ny * nz;           // <= 64

        int cnt = 0, cellid = 0;
        if (lane < ncell) {
            int t = lane;
            const int dz = t % nz; t /= nz;
            const int dy = t % ny; t /= ny;
            const int dx = t;
            cellid = ((cxlo + dx) * GD + (cylo + dy)) * GD + (czlo + dz);
            const unsigned raw = g_counts[cellid];
            cnt = ((raw >> 8) == gen) ? min((int)(raw & 0xFFu), CAP) : 0;
        }

        const int incl = wave_incl_scan_i(cnt);
        const int T    = __builtin_amdgcn_readlane(incl, 63);
        const int excl = incl - cnt;
        // Monotone payload: inclusive max-scan resolves candidate -> owner.
        const int pack = (excl << 13) | cellid;   // excl<=1024, cell<8192
        const bool pusher = (lane < ncell) && (cnt > 0);

        float csum = 0.0f;
        float acc[MAXB];
#pragma unroll
        for (int b = 0; b < MAXB; ++b) acc[b] = 0.0f;

        int seed = 0;
        for (int base = 0; base < T; base += 64) {    // typ. 1 pass (T ~ 55)
            const int t = base + lane;
            const bool act = t < T;

            M[lane] = 0;
            __builtin_amdgcn_wave_barrier();
            if (pusher && (unsigned)(excl - base) < 64u)
                M[excl - base] = pack;
            __builtin_amdgcn_wave_barrier();
            int r = M[lane];
            if (lane == 0) r = ((unsigned)r > (unsigned)seed) ? r : seed;
            const int own = wave_incl_maxscan_u(r);
            seed = __builtin_amdgcn_readlane(own, 63);

            const int ej = (unsigned)own >> 13;
            const int cj = own & 0x1FFF;
            float4 cand = make_float4(1e9f, 1e9f, 1e9f, 0.0f);
            if (act) cand = bins[(size_t)cj * CAP + (t - ej)];
            // identical membership expression to validated rounds
            const float dx = ox - cand.x;
            const float dy = oy - cand.y;
            const float dz = oz - cand.z;
            const float d2 = dx * dx + dy * dy + dz * dz;
            if (d2 <= r2) {
                csum += 1.0f;
                const int idx = __float_as_int(cand.w);
                const float4* xv = (const float4*)(xT + (size_t)idx * MAXB);
                const float4 a = xv[0], b4 = xv[1];
                acc[0] += a.x;  acc[1] += a.y;  acc[2] += a.z;  acc[3] += a.w;
                acc[4] += b4.x; acc[5] += b4.y; acc[6] += b4.z; acc[7] += b4.w;
            }
        }

        const float tc = wave_sum_f(csum);
        const float t0 = wave_sum_f(acc[0]);
        const float t1 = wave_sum_f(acc[1]);
        const float t2 = wave_sum_f(acc[2]);
        const float t3 = wave_sum_f(acc[3]);
        const float t4 = wave_sum_f(acc[4]);
        const float t5 = wave_sum_f(acc[5]);
        const float t6 = wave_sum_f(acc[6]);
        const float t7 = wave_sum_f(acc[7]);

        const float cc = (tc > 0.0f) ? tc : 1.0f;
        float v = t0;
        v = (lane == 1) ? t1 : v;
        v = (lane == 2) ? t2 : v;
        v = (lane == 3) ? t3 : v;
        v = (lane == 4) ? t4 : v;
        v = (lane == 5) ? t5 : v;
        v = (lane == 6) ? t6 : v;
        v = (lane == 7) ? t7 : v;
        if (lane < B) out[(size_t)lane * n_out + o] = v / cc;
    }

    // Last-finishing block advances the generation for the NEXT iteration.
    // No query block reads g_gen, so the bump cannot race with its readers.
    __syncthreads();
    if (threadIdx.x == 0) {
        const unsigned old = atomicAdd(&g_done, 1u);
        if (old == (unsigned)gridDim.x - 1u) {
            g_done = 0u;
            g_gen  = gen + 1u;
        }
    }
}

// --- safety-net brute kernel (only if ws too small / B > 8) -----------------
__global__ void __launch_bounds__(TPB) brute_kernel(
    const float* __restrict__ x, const float* __restrict__ ip,
    const float* __restrict__ op, float* __restrict__ out,
    int B, int n_in, int n_out, float r2)
{
    const int o = blockIdx.x * TPB + (int)threadIdx.x;
    if (o >= n_out) return;
    const float ox = op[3 * o], oy = op[3 * o + 1], oz = op[3 * o + 2];
    float cnt = 0.0f, acc[MAXB];
#pragma unroll
    for (int b = 0; b < MAXB; ++b) acc[b] = 0.0f;
    for (int i = 0; i < n_in; ++i) {
        const float dx = ox - ip[3 * i];
        const float dy = oy - ip[3 * i + 1];
        const float dz = oz - ip[3 * i + 2];
        const float d2 = dx * dx + dy * dy + dz * dz;
        if (d2 <= r2) {
            cnt += 1.0f;
            for (int b = 0; b < B && b < MAXB; ++b) acc[b] += x[(size_t)b * n_in + i];
        }
    }
    const float cc = (cnt > 0.0f) ? cnt : 1.0f;
    for (int b = 0; b < B && b < MAXB; ++b)
        out[(size_t)b * n_out + o] = acc[b] / cc;
}

// --- host --------------------------------------------------------------------
extern "C" void kernel_launch(void* const* d_in, const int* in_sizes, int n_in_args,
                              void* d_out, int out_size, void* d_ws, size_t ws_size,
                              hipStream_t stream) {
    const float* x  = (const float*)d_in[0];
    const float* ip = (const float*)d_in[1];
    const float* op = (const float*)d_in[2];
    float* out = (float*)d_out;

    const int n_in  = in_sizes[1] / 3;
    const int n_out = in_sizes[2] / 3;
    const int B     = in_sizes[0] / n_in;
    const float r2  = (float)(0.05 * 0.05);

    // Workspace layout: [bins 2MB] [xT]  (counts live in static g_counts)
    const size_t bins_b = (size_t)NC * CAP * sizeof(float4);   // 2 MB
    const size_t xT_b   = (size_t)n_in * MAXB * sizeof(float);
    const size_t need   = bins_b + xT_b;

    if (B <= MAXB && ws_size >= need) {
        float4* bins = (float4*)d_ws;
        float*  xT   = (float*)((char*)d_ws + bins_b);

        // 2 dispatches: generation-tagged counts need no memset.
        bin_kernel<<<cdiv(n_in, BINT), BINT, 0, stream>>>(x, ip, bins, xT, B, n_in);
        query_kernel<<<cdiv(n_out, 4), TPB, 0, stream>>>(bins, xT, op, out,
                                                         B, n_out, r2);
    } else {
        brute_kernel<<<cdiv(n_out, TPB), TPB, 0, stream>>>(x, ip, op, out,
                                                           B, n_in, n_out, r2);
    }
}

// Round 8
// 68.139 us; speedup vs baseline: 1.3483x; 1.3483x over previous
//
#include <hip/hip_runtime.h>

#define TPB   256
#define BINT  64     // bin kernel block size: 64-thr blocks spread over 256 CUs
#define MAXB  8
#define GD    20
#define NC    (GD * GD * GD)
#define CAP   16     // Poisson(2.05) max over 8000 cells ~13; P(>16) ~ 6e-7. 2MB bins.

static inline int cdiv(int a, int b) { return (a + b - 1) / b; }

// --- DPP cross-lane helpers (rocPRIM wave64 pattern) ------------------------
// NB: __builtin_amdgcn_update_dpp requires LITERAL ctrl/rmask -> macros/templates.
#define DPP_ADD_I(x, ctrl, rmask)                                             \
    ((x) + __builtin_amdgcn_update_dpp(0, (x), (ctrl), (rmask), 0xf, true))
#define DPP_ADD_F(x, ctrl, rmask)                                             \
    ((x) + __int_as_float(__builtin_amdgcn_update_dpp(                        \
               0, __float_as_int(x), (ctrl), (rmask), 0xf, true)))

__device__ __forceinline__ int wave_incl_scan_i(int x) {
    x = DPP_ADD_I(x, 0x111, 0xf);   // row_shr:1
    x = DPP_ADD_I(x, 0x112, 0xf);   // row_shr:2
    x = DPP_ADD_I(x, 0x114, 0xf);   // row_shr:4
    x = DPP_ADD_I(x, 0x118, 0xf);   // row_shr:8
    x = DPP_ADD_I(x, 0x142, 0xa);   // row_bcast:15
    x = DPP_ADD_I(x, 0x143, 0xc);   // row_bcast:31
    return x;
}

template <int CTRL, int RMASK>
__device__ __forceinline__ int dpp_max_step(int x) {
    const int y = __builtin_amdgcn_update_dpp(0, x, CTRL, RMASK, 0xf, true);
    return ((unsigned)x > (unsigned)y) ? x : y;
}
__device__ __forceinline__ int wave_incl_maxscan_u(int x) {
    x = dpp_max_step<0x111, 0xf>(x);
    x = dpp_max_step<0x112, 0xf>(x);
    x = dpp_max_step<0x114, 0xf>(x);
    x = dpp_max_step<0x118, 0xf>(x);
    x = dpp_max_step<0x142, 0xa>(x);
    x = dpp_max_step<0x143, 0xc>(x);
    return x;
}

__device__ __forceinline__ float wave_sum_f(float x) {
    x = DPP_ADD_F(x, 0x111, 0xf);
    x = DPP_ADD_F(x, 0x112, 0xf);
    x = DPP_ADD_F(x, 0x114, 0xf);
    x = DPP_ADD_F(x, 0x118, 0xf);
    x = DPP_ADD_F(x, 0x142, 0xa);
    x = DPP_ADD_F(x, 0x143, 0xc);
    return __int_as_float(__builtin_amdgcn_readlane(__float_as_int(x), 63));
}

// --- bin + transpose kernel --------------------------------------------------
// bins[cell][slot] = (px,py,pz, bitcast(i)); xT[i][0..7] = x[b][i] (0 for b>=B)
__global__ void __launch_bounds__(BINT) bin_kernel(
    const float* __restrict__ x, const float* __restrict__ ip,
    int* __restrict__ counts, float4* __restrict__ bins,
    float* __restrict__ xT, int B, int n_in)
{
    const int i = blockIdx.x * BINT + (int)threadIdx.x;
    if (i >= n_in) return;
    const float px = ip[3 * i], py = ip[3 * i + 1], pz = ip[3 * i + 2];
    const int cx = min(GD - 1, max(0, (int)(px * (float)GD)));
    const int cy = min(GD - 1, max(0, (int)(py * (float)GD)));
    const int cz = min(GD - 1, max(0, (int)(pz * (float)GD)));
    const int cell = (cx * GD + cy) * GD + cz;
    const int slot = atomicAdd(counts + cell, 1);
    if (slot < CAP)   // query clamps count to CAP; overflow prob ~6e-7
        bins[(size_t)cell * CAP + slot] = make_float4(px, py, pz, __int_as_float(i));
    float v[MAXB];
#pragma unroll
    for (int b = 0; b < MAXB; ++b)
        v[b] = (b < B) ? x[(size_t)b * n_in + i] : 0.0f;
    float4* dst = (float4*)(xT + (size_t)i * MAXB);
    dst[0] = make_float4(v[0], v[1], v[2], v[3]);
    dst[1] = make_float4(v[4], v[5], v[6], v[7]);
}

// --- query kernel: one wave per output point --------------------------------
__global__ void __launch_bounds__(TPB) query_kernel(
    const int* __restrict__ counts, const float4* __restrict__ bins,
    const float* __restrict__ xT, const float* __restrict__ out_pos,
    float* __restrict__ out, int B, int n_out, float r2)
{
    // Per-wave 64-slot scatter buffer for owner resolution (1 KB/block).
    __shared__ int Msh[TPB / 64][64];

    const int lane = (int)threadIdx.x & 63;
    const int wid  = (int)threadIdx.x >> 6;
    const int o    = blockIdx.x * 4 + wid;
    if (o >= n_out) return;                       // wave-uniform exit

    volatile int* M = &Msh[wid][0];

    const float ox = out_pos[3 * o];
    const float oy = out_pos[3 * o + 1];
    const float oz = out_pos[3 * o + 2];

    // Cell ranges from [o-r-m, o+r+m]; margin m covers fp slop on the
    // d2<=r2 boundary. Worst span 4 cells/axis -> ncell<=64.
    const float m = 0.05f + 1e-4f;
    const int cxlo = max(0, (int)floorf((ox - m) * (float)GD));
    const int cxhi = min(GD - 1, (int)floorf((ox + m) * (float)GD));
    const int cylo = max(0, (int)floorf((oy - m) * (float)GD));
    const int cyhi = min(GD - 1, (int)floorf((oy + m) * (float)GD));
    const int czlo = max(0, (int)floorf((oz - m) * (float)GD));
    const int czhi = min(GD - 1, (int)floorf((oz + m) * (float)GD));
    const int nx = cxhi - cxlo + 1, ny = cyhi - cylo + 1, nz = czhi - czlo + 1;
    const int ncell = nx * ny * nz;               // <= 64

    int cnt = 0, cellid = 0;
    if (lane < ncell) {
        int t = lane;
        const int dz = t % nz; t /= nz;
        const int dy = t % ny; t /= ny;
        const int dx = t;
        cellid = ((cxlo + dx) * GD + (cylo + dy)) * GD + (czlo + dz);
        cnt = min(counts[cellid], CAP);
    }

    const int incl = wave_incl_scan_i(cnt);
    const int T    = __builtin_amdgcn_readlane(incl, 63);
    const int excl = incl - cnt;
    // Monotone payload: inclusive max-scan resolves candidate -> owner.
    const int pack = (excl << 13) | cellid;       // excl<=1024, cell<8192
    const bool pusher = (lane < ncell) && (cnt > 0);

    float csum = 0.0f;
    float acc[MAXB];
#pragma unroll
    for (int b = 0; b < MAXB; ++b) acc[b] = 0.0f;

    int seed = 0;
    for (int base = 0; base < T; base += 64) {    // typ. 1 pass (T ~ 55)
        const int t = base + lane;
        const bool act = t < T;

        M[lane] = 0;
        __builtin_amdgcn_wave_barrier();
        if (pusher && (unsigned)(excl - base) < 64u)
            M[excl - base] = pack;
        __builtin_amdgcn_wave_barrier();
        int r = M[lane];
        if (lane == 0) r = ((unsigned)r > (unsigned)seed) ? r : seed;
        const int own = wave_incl_maxscan_u(r);
        seed = __builtin_amdgcn_readlane(own, 63);

        const int ej = (unsigned)own >> 13;
        const int cj = own & 0x1FFF;
        float4 cand = make_float4(1e9f, 1e9f, 1e9f, 0.0f);
        if (act) cand = bins[(size_t)cj * CAP + (t - ej)];
        // identical membership expression to validated rounds
        const float dx = ox - cand.x;
        const float dy = oy - cand.y;
        const float dz = oz - cand.z;
        const float d2 = dx * dx + dy * dy + dz * dz;

        // Unconditional xT gather: idx is 0 for the dummy candidate (cand.w
        // bitcast) so the address is always valid; issuing the load before
        // the d2 compare resolves shortens the serial chain. Accumulation is
        // predicated, so hit-lane arithmetic (and absmax) is unchanged.
        const int idx = __float_as_int(cand.w);
        const float4* xv = (const float4*)(xT + (size_t)idx * MAXB);
        const float4 a = xv[0], b4 = xv[1];
        const bool hit = (d2 <= r2);
        const float w = hit ? 1.0f : 0.0f;
        csum += w;
        acc[0] += hit ? a.x  : 0.0f;
        acc[1] += hit ? a.y  : 0.0f;
        acc[2] += hit ? a.z  : 0.0f;
        acc[3] += hit ? a.w  : 0.0f;
        acc[4] += hit ? b4.x : 0.0f;
        acc[5] += hit ? b4.y : 0.0f;
        acc[6] += hit ? b4.z : 0.0f;
        acc[7] += hit ? b4.w : 0.0f;
    }

    const float tc = wave_sum_f(csum);
    const float t0 = wave_sum_f(acc[0]);
    const float t1 = wave_sum_f(acc[1]);
    const float t2 = wave_sum_f(acc[2]);
    const float t3 = wave_sum_f(acc[3]);
    const float t4 = wave_sum_f(acc[4]);
    const float t5 = wave_sum_f(acc[5]);
    const float t6 = wave_sum_f(acc[6]);
    const float t7 = wave_sum_f(acc[7]);

    const float cc = (tc > 0.0f) ? tc : 1.0f;
    float v = t0;
    v = (lane == 1) ? t1 : v;
    v = (lane == 2) ? t2 : v;
    v = (lane == 3) ? t3 : v;
    v = (lane == 4) ? t4 : v;
    v = (lane == 5) ? t5 : v;
    v = (lane == 6) ? t6 : v;
    v = (lane == 7) ? t7 : v;
    if (lane < B) out[(size_t)lane * n_out + o] = v / cc;
}

// --- safety-net brute kernel (only if ws too small / B > 8) -----------------
__global__ void __launch_bounds__(TPB) brute_kernel(
    const float* __restrict__ x, const float* __restrict__ ip,
    const float* __restrict__ op, float* __restrict__ out,
    int B, int n_in, int n_out, float r2)
{
    const int o = blockIdx.x * TPB + (int)threadIdx.x;
    if (o >= n_out) return;
    const float ox = op[3 * o], oy = op[3 * o + 1], oz = op[3 * o + 2];
    float cnt = 0.0f, acc[MAXB];
#pragma unroll
    for (int b = 0; b < MAXB; ++b) acc[b] = 0.0f;
    for (int i = 0; i < n_in; ++i) {
        const float dx = ox - ip[3 * i];
        const float dy = oy - ip[3 * i + 1];
        const float dz = oz - ip[3 * i + 2];
        const float d2 = dx * dx + dy * dy + dz * dz;
        if (d2 <= r2) {
            cnt += 1.0f;
            for (int b = 0; b < B && b < MAXB; ++b) acc[b] += x[(size_t)b * n_in + i];
        }
    }
    const float cc = (cnt > 0.0f) ? cnt : 1.0f;
    for (int b = 0; b < B && b < MAXB; ++b)
        out[(size_t)b * n_out + o] = acc[b] / cc;
}

// --- host --------------------------------------------------------------------
extern "C" void kernel_launch(void* const* d_in, const int* in_sizes, int n_in_args,
                              void* d_out, int out_size, void* d_ws, size_t ws_size,
                              hipStream_t stream) {
    const float* x  = (const float*)d_in[0];
    const float* ip = (const float*)d_in[1];
    const float* op = (const float*)d_in[2];
    float* out = (float*)d_out;

    const int n_in  = in_sizes[1] / 3;
    const int n_out = in_sizes[2] / 3;
    const int B     = in_sizes[0] / n_in;
    const float r2  = (float)(0.05 * 0.05);

    // Workspace layout: [counts, pad -> 32768] [bins 2MB] [xT]
    const size_t counts_b = 32768;                               // NC*4 padded
    const size_t bins_b   = (size_t)NC * CAP * sizeof(float4);   // 2 MB
    const size_t xT_b     = (size_t)n_in * MAXB * sizeof(float);
    const size_t need     = counts_b + bins_b + xT_b;

    if (B <= MAXB && ws_size >= need) {
        int*    counts = (int*)d_ws;
        float4* bins   = (float4*)((char*)d_ws + counts_b);
        float*  xT     = (float*)((char*)d_ws + counts_b + bins_b);

        (void)hipMemsetAsync(counts, 0, (size_t)NC * sizeof(int), stream);
        bin_kernel<<<cdiv(n_in, BINT), BINT, 0, stream>>>(x, ip, counts, bins, xT,
                                                          B, n_in);
        query_kernel<<<cdiv(n_out, 4), TPB, 0, stream>>>(counts, bins, xT, op, out,
                                                         B, n_out, r2);
    } else {
        brute_kernel<<<cdiv(n_out, TPB), TPB, 0, stream>>>(x, ip, op, out,
                                                           B, n_in, n_out, r2);
    }
}